// Round 4
// baseline (415.329 us; speedup 1.0000x reference)
//
#include <hip/hip_runtime.h>
#include <cmath>

// ---------------------------------------------------------------------------
// Types / helpers
// ---------------------------------------------------------------------------
typedef __attribute__((ext_vector_type(8))) short bf16x8;   // 8 bf16 = 4 VGPRs
typedef __attribute__((ext_vector_type(4))) float f32x4;

__device__ __forceinline__ unsigned short f2b(float f) {   // RNE (cold paths)
    union { float f; unsigned u; } c; c.f = f;
    unsigned r = (c.u + 0x7FFFu + ((c.u >> 16) & 1u)) >> 16;
    return (unsigned short)r;
}
__device__ __forceinline__ unsigned short f2b_hu(float f) { // round-half-up, 2 VALU
    union { float f; unsigned u; } c; c.f = f;
    return (unsigned short)((c.u + 0x8000u) >> 16);
}
__device__ __forceinline__ unsigned pk2(float a, float b) { // pack 2 bf16 (half-up)
    union { float f; unsigned u; } x, y; x.f = a; y.f = b;
    return ((x.u + 0x8000u) >> 16) | (((y.u + 0x8000u) >> 16) << 16);
}
__device__ __forceinline__ float b2f(unsigned short h) {
    union { unsigned u; float f; } c; c.u = ((unsigned)h) << 16;
    return c.f;
}

// async global->LDS 16B (wave-uniform LDS base + lane*16)
__device__ __forceinline__ void gl2lds16(const unsigned short* g, unsigned short* l) {
    __builtin_amdgcn_global_load_lds(
        (const __attribute__((address_space(1))) unsigned int*)(g),
        (__attribute__((address_space(3))) unsigned int*)(l),
        16, 0, 0);
}

// Problem constants
#define BB   4
#define NN   2048
#define DD   512
#define HH   8
#define DH   64
#define DFF  2048
#define ROWS (BB * NN)          // 8192
#define SCALE_QK 0.044194173824159216f   // 1/sqrt(512)

// ---------------------------------------------------------------------------
// LayerNorm (fp32 in) -> bf16 out.  One block (256 thr) per row of 512.
// ---------------------------------------------------------------------------
__global__ __launch_bounds__(256)
void ln_kernel(const float* __restrict__ X, const float* __restrict__ g,
               const float* __restrict__ be, unsigned short* __restrict__ out)
{
    __shared__ float sred[8];
    const int row = blockIdx.x;
    const int tid = threadIdx.x;
    const float* x = X + (size_t)row * DD;
    float x0 = x[tid], x1 = x[tid + 256];
    float s = x0 + x1, sq = x0 * x0 + x1 * x1;
#pragma unroll
    for (int off = 32; off; off >>= 1) {
        s  += __shfl_down(s,  off);
        sq += __shfl_down(sq, off);
    }
    const int wid = tid >> 6;
    if ((tid & 63) == 0) { sred[wid] = s; sred[4 + wid] = sq; }
    __syncthreads();
    float ts = 0.f, tq = 0.f;
#pragma unroll
    for (int i = 0; i < 4; ++i) { ts += sred[i]; tq += sred[4 + i]; }
    const float mean = ts * (1.0f / DD);
    const float var  = tq * (1.0f / DD) - mean * mean;
    const float rinv = rsqrtf(var + 1e-5f);
    unsigned short* o = out + (size_t)row * DD;
    o[tid]       = f2b((x0 - mean) * rinv * g[tid]       + be[tid]);
    o[tid + 256] = f2b((x1 - mean) * rinv * g[tid + 256] + be[tid + 256]);
}

// ---------------------------------------------------------------------------
// fp32 -> bf16 elementwise cast (4 elems/thread)
// ---------------------------------------------------------------------------
__global__ __launch_bounds__(256)
void cast_bf16_kernel(const float* __restrict__ in, unsigned short* __restrict__ out, int n4)
{
    int i = blockIdx.x * 256 + threadIdx.x;
    if (i < n4) {
        float4 v = ((const float4*)in)[i];
        ushort4 o;
        o.x = f2b(v.x); o.y = f2b(v.y); o.z = f2b(v.z); o.w = f2b(v.w);
        ((ushort4*)out)[i] = o;
    }
}

// ---------------------------------------------------------------------------
// Transpose + cast: W[K][Nn] fp32 -> Wt[Nn][K] bf16.  32x32 LDS tiles.
// ---------------------------------------------------------------------------
__global__ __launch_bounds__(256)
void transpose_cast_kernel(const float* __restrict__ W, unsigned short* __restrict__ Wt,
                           int K, int Nn)
{
    __shared__ float tile[32][33];
    const int n0 = blockIdx.x * 32, k0 = blockIdx.y * 32;
    const int tx = threadIdx.x & 31, ty = threadIdx.x >> 5;  // ty 0..7
#pragma unroll
    for (int i = 0; i < 4; ++i)
        tile[ty + i * 8][tx] = W[(size_t)(k0 + ty + i * 8) * Nn + n0 + tx];
    __syncthreads();
#pragma unroll
    for (int i = 0; i < 4; ++i)
        Wt[(size_t)(n0 + ty + i * 8) * K + k0 + tx] = f2b(tile[tx][ty + i * 8]);
}

// concat biases bq|bk|bv -> bqkv[1536]
__global__ __launch_bounds__(256)
void bias_concat_kernel(const float* __restrict__ bq, const float* __restrict__ bk,
                        const float* __restrict__ bv, float* __restrict__ o)
{
    int i = blockIdx.x * 256 + threadIdx.x;   // 0..1535
    float v = (i < 512) ? bq[i] : (i < 1024) ? bk[i - 512] : bv[i - 1024];
    o[i] = v;
}

// ---------------------------------------------------------------------------
// GEMM: C[M,N] = A[M,K] @ Bt[N,K]^T + bias, bf16 in, fp32 accumulate.
// 128x128 tile, 256 threads (4 waves 2x2), BK=64 (two 128x32 LDS halves),
// global_load_lds width-16 async staging.  (unchanged from round 3)
// MODE 1: += bf16 residual (resB), store fp32 (outF)            [mix]
// MODE 2: fast-tanh gelu, store bf16 (outB)                     [FFN1]
// MODE 3: += fp32 residual (resF), store fp32 (outF)            [FFN2]
// MODE 4: fused QKV, N=1536: col<512 -> Qb, <1024 -> Kbf, else V transposed
//         into Vtg[b*512+feat][token]; A = (by<4) ? A0 : A1.
// ---------------------------------------------------------------------------
#define BK 64

template <int MODE>
__global__ __launch_bounds__(256)
void gemm_bt(const unsigned short* __restrict__ A0, const unsigned short* __restrict__ A1,
             const unsigned short* __restrict__ Bt,
             const float* __restrict__ bias,
             const unsigned short* __restrict__ resB, const float* __restrict__ resF,
             unsigned short* __restrict__ outB, float* __restrict__ outF,
             unsigned short* __restrict__ outQ, unsigned short* __restrict__ outK,
             unsigned short* __restrict__ outVt,
             int M, int N, int K)
{
    __shared__ __align__(16) unsigned short As[2][128 * 32];
    __shared__ __align__(16) unsigned short Bs[2][128 * 32];
    const int tid  = threadIdx.x;
    const int wave = tid >> 6, lane = tid & 63;
    const int quad = lane >> 4, l16 = lane & 15;
    const int wm = (wave & 1) * 64, wn = (wave >> 1) * 64;
    const int m0 = blockIdx.x * 128, n0 = blockIdx.y * 128;

    const unsigned short* A = (MODE == 4 && blockIdx.y >= 4) ? A1 : A0;

    const int srow = lane >> 2;
    const int sc8  = (lane & 3) * 8;
    const unsigned short* gA = A  + (size_t)(m0 + wave * 32 + srow) * K + sc8;
    const unsigned short* gB = Bt + (size_t)(n0 + wave * 32 + srow) * K + sc8;

    f32x4 acc[4][4];
#pragma unroll
    for (int i = 0; i < 4; ++i)
#pragma unroll
        for (int j = 0; j < 4; ++j)
            acc[i][j] = (f32x4){0.f, 0.f, 0.f, 0.f};

    for (int kk = 0; kk < K; kk += BK) {
        __syncthreads();
#pragma unroll
        for (int i = 0; i < 4; ++i) {
            const int half = i & 1;
            const int rb   = wave * 32 + (i >> 1) * 16;
            const size_t gsh = (size_t)(i >> 1) * 16 * K + half * 32 + kk;
            gl2lds16(gA + gsh, &As[half][rb * 32]);
            gl2lds16(gB + gsh, &Bs[half][rb * 32]);
        }
        __syncthreads();
#pragma unroll
        for (int h = 0; h < 2; ++h) {
            bf16x8 a[4], b[4];
#pragma unroll
            for (int i = 0; i < 4; ++i)
                a[i] = *(const bf16x8*)&As[h][(wm + i * 16 + l16) * 32 + quad * 8];
#pragma unroll
            for (int j = 0; j < 4; ++j)
                b[j] = *(const bf16x8*)&Bs[h][(wn + j * 16 + l16) * 32 + quad * 8];
#pragma unroll
            for (int i = 0; i < 4; ++i)
#pragma unroll
                for (int j = 0; j < 4; ++j)
                    acc[i][j] = __builtin_amdgcn_mfma_f32_16x16x32_bf16(a[i], b[j], acc[i][j], 0, 0, 0);
        }
    }

    // Epilogue. C/D layout: col = lane&15, row = quad*4 + reg.
#pragma unroll
    for (int i = 0; i < 4; ++i) {
#pragma unroll
        for (int j = 0; j < 4; ++j) {
            const int col  = n0 + wn + j * 16 + l16;
            const int row0 = m0 + wm + i * 16 + quad * 4;
            const float bsv = bias[col];
            if (MODE == 4) {
                if (col < DD) {
#pragma unroll
                    for (int r = 0; r < 4; ++r)
                        outQ[(size_t)(row0 + r) * DD + col] = f2b_hu(acc[i][j][r] + bsv);
                } else if (col < 2 * DD) {
#pragma unroll
                    for (int r = 0; r < 4; ++r)
                        outK[(size_t)(row0 + r) * DD + (col - DD)] = f2b_hu(acc[i][j][r] + bsv);
                } else {
                    const int feat = col - 2 * DD;
                    const int bb = row0 >> 11;
                    const int n  = row0 & (NN - 1);
                    ushort4 o;
                    o.x = f2b_hu(acc[i][j][0] + bsv);
                    o.y = f2b_hu(acc[i][j][1] + bsv);
                    o.z = f2b_hu(acc[i][j][2] + bsv);
                    o.w = f2b_hu(acc[i][j][3] + bsv);
                    *(ushort4*)&outVt[((size_t)bb * DD + feat) * NN + n] = o;
                }
            } else {
#pragma unroll
                for (int r = 0; r < 4; ++r) {
                    const size_t idx = (size_t)(row0 + r) * N + col;
                    float v = acc[i][j][r] + bsv;
                    if (MODE == 1) {
                        outF[idx] = v + b2f(resB[idx]);
                    } else if (MODE == 2) {
                        float u = 0.7978845608028654f * (v + 0.044715f * v * v * v);
                        float e = __expf(2.0f * u);
                        float t = 1.0f - 2.0f / (e + 1.0f);
                        outB[idx] = f2b_hu(0.5f * v * (1.0f + t));
                    } else {   // MODE 3
                        outF[idx] = v + resF[idx];
                    }
                }
            }
        }
    }
}

// ---------------------------------------------------------------------------
// Flash attention v4: one block = (b, h, 128-query tile), 4 waves, wave w
// owns q rows w*32..w*32+31 (two 16-q subtiles).
// ALL MFMA fragments load DIRECTLY from global (16B-contiguous runs):
//   K A-frag  : Kb [(b*2048+kv)*512 + h*64 + dh8..]      (L1 absorbs 4-wave reuse)
//   Q B-frag  : Qb — hoisted into registers before the loop
//   V^T A-frag: Vtg[(b*512+h*64+dh)*2048 + kv8..]
// No LDS staging, NO __syncthreads in the loop — compiler pipelines global
// loads on vmcnt.  Only P^T round-trips through wave-private LDS (packed
// b32, stride-33 dwords).  S^T orientation (K*Q^T): lane = one q column ->
// scalar lsum; scale folded into exp argument.  O accumulates as O^T;
// one wave-private LDS transpose at the end.
// ---------------------------------------------------------------------------
#define PLD 33   // Pt row stride in dwords

__global__ __launch_bounds__(256)
void flash_attn_kernel(const unsigned short* __restrict__ Q,
                       const unsigned short* __restrict__ Kb,
                       const unsigned short* __restrict__ Vtg,
                       unsigned short* __restrict__ O)
{
    __shared__ __align__(16) unsigned int Pt[4 * 32 * PLD];   // 16.9 KB

    const int tid  = threadIdx.x;
    const int wave = tid >> 6, lane = tid & 63;
    const int quad = lane >> 4, l16 = lane & 15;

    const int bid = blockIdx.x;
    const int qt = bid & 15;          // 16 q-tiles of 128
    const int bh = bid >> 4;
    const int b  = bh >> 3;
    const int h  = bh & 7;
    const size_t rowbase = (size_t)b * NN * DD;
    const int q0 = qt * 128 + wave * 32;   // this wave's q base
    const int hc = h * DD / 8;             // h*64
    unsigned int* myPt = &Pt[wave * 32 * PLD];

    // hoist Q B-frags: [subtile t][hh]  (q = q0 + t*16 + l16, dh = hh*32+quad*8)
    bf16x8 Qf[2][2];
#pragma unroll
    for (int t = 0; t < 2; ++t)
#pragma unroll
        for (int hh = 0; hh < 2; ++hh)
            Qf[t][hh] = *(const bf16x8*)&Q[rowbase + (size_t)(q0 + t * 16 + l16) * DD
                                           + hc + hh * 32 + quad * 8];

    f32x4 Oacc[2][4];   // [subtile t][dh-tile t2]: O^T, col=q(l16), row=dh=16*t2+4*quad+r
#pragma unroll
    for (int t = 0; t < 2; ++t)
#pragma unroll
        for (int t2 = 0; t2 < 4; ++t2) Oacc[t][t2] = (f32x4){0.f, 0.f, 0.f, 0.f};
    float lsum[2] = {0.f, 0.f};

    // per-lane global bases
    const unsigned short* gK = Kb + rowbase + (size_t)l16 * DD + hc + quad * 8;
    const unsigned short* gV = Vtg + ((size_t)b * DD + hc + l16) * NN + quad * 8;

    for (int kt = 0; kt < NN / 64; ++kt) {
        const int kv0 = kt * 64;

        // ---- S^T = K · Q^T, per j-tile of 16 kv ----
        f32x4 St[2][4];
#pragma unroll
        for (int t = 0; t < 2; ++t)
#pragma unroll
            for (int j = 0; j < 4; ++j) St[t][j] = (f32x4){0.f, 0.f, 0.f, 0.f};
#pragma unroll
        for (int j = 0; j < 4; ++j) {
#pragma unroll
            for (int hh = 0; hh < 2; ++hh) {
                bf16x8 kf = *(const bf16x8*)&gK[(size_t)(kv0 + j * 16) * DD + hh * 32];
#pragma unroll
                for (int t = 0; t < 2; ++t)
                    St[t][j] = __builtin_amdgcn_mfma_f32_16x16x32_bf16(kf, Qf[t][hh], St[t][j], 0, 0, 0);
            }
        }

        // ---- exp(scale*S), scalar lsum, pack P^T into wave-private LDS ----
#pragma unroll
        for (int t = 0; t < 2; ++t) {
            unsigned int* rowp = &myPt[(t * 16 + l16) * PLD];
#pragma unroll
            for (int j = 0; j < 4; ++j) {
                float p0 = __expf(St[t][j][0] * SCALE_QK);
                float p1 = __expf(St[t][j][1] * SCALE_QK);
                float p2 = __expf(St[t][j][2] * SCALE_QK);
                float p3 = __expf(St[t][j][3] * SCALE_QK);
                lsum[t] += (p0 + p1) + (p2 + p3);
                rowp[j * 8 + quad * 2]     = pk2(p0, p1);
                rowp[j * 8 + quad * 2 + 1] = pk2(p2, p3);
            }
        }

        // ---- O^T += V^T · P^T ----
#pragma unroll
        for (int ks = 0; ks < 2; ++ks) {
            bf16x8 pf[2];
#pragma unroll
            for (int t = 0; t < 2; ++t)
                pf[t] = *(const bf16x8*)&myPt[(t * 16 + l16) * PLD + ks * 16 + quad * 4];
#pragma unroll
            for (int t2 = 0; t2 < 4; ++t2) {
                bf16x8 vf = *(const bf16x8*)&gV[(size_t)t2 * 16 * NN + kv0 + ks * 32];
#pragma unroll
                for (int t = 0; t < 2; ++t)
                    Oacc[t][t2] = __builtin_amdgcn_mfma_f32_16x16x32_bf16(vf, pf[t], Oacc[t][t2], 0, 0, 0);
            }
        }
    }

    // reduce lsum across the 4 quads (same q = l16)
#pragma unroll
    for (int t = 0; t < 2; ++t) {
        lsum[t] += __shfl_xor(lsum[t], 16);
        lsum[t] += __shfl_xor(lsum[t], 32);
    }
    const float rl0 = 1.0f / lsum[0], rl1 = 1.0f / lsum[1];

    // transpose O^T -> O via wave-private LDS (reuse Pt region), then store
#pragma unroll
    for (int t = 0; t < 2; ++t) {
        const float rl = t ? rl1 : rl0;
        unsigned int* rowp = &myPt[(t * 16 + l16) * PLD];
#pragma unroll
        for (int t2 = 0; t2 < 4; ++t2) {
            rowp[t2 * 8 + quad * 2]     = pk2(Oacc[t][t2][0] * rl, Oacc[t][t2][1] * rl);
            rowp[t2 * 8 + quad * 2 + 1] = pk2(Oacc[t][t2][2] * rl, Oacc[t][t2][3] * rl);
        }
    }
    // wave-private read-back + coalesced global store (no barrier needed)
#pragma unroll
    for (int ii = 0; ii < 4; ++ii) {
        int flat  = lane + ii * 64;       // 0..255
        int row   = flat >> 3;            // 0..31  (q within wave)
        int chunk = flat & 7;             // 8B-dword chunks of the 64-dh row
        uint4 v = *(const uint4*)&myPt[row * PLD + chunk * 4];
        *(uint4*)&O[rowbase + (size_t)(q0 + row) * DD + hc + chunk * 8] = v;
    }
}

// ---------------------------------------------------------------------------
// Launch
// ---------------------------------------------------------------------------
extern "C" void kernel_launch(void* const* d_in, const int* in_sizes, int n_in,
                              void* d_out, int out_size, void* d_ws, size_t ws_size,
                              hipStream_t stream)
{
    (void)in_sizes; (void)n_in; (void)out_size; (void)ws_size;

    const float* X   = (const float*)d_in[0];
    const float* Y   = (const float*)d_in[1];
    const float* Wq  = (const float*)d_in[2];
    const float* bq  = (const float*)d_in[3];
    const float* Wk  = (const float*)d_in[4];
    const float* bk  = (const float*)d_in[5];
    const float* Wv  = (const float*)d_in[6];
    const float* bv  = (const float*)d_in[7];
    const float* Wm  = (const float*)d_in[8];
    const float* bm  = (const float*)d_in[9];
    const float* g0  = (const float*)d_in[10];
    const float* b0  = (const float*)d_in[11];
    const float* g1  = (const float*)d_in[12];
    const float* b1  = (const float*)d_in[13];
    const float* W1  = (const float*)d_in[14];
    const float* bb1 = (const float*)d_in[15];
    const float* W2  = (const float*)d_in[16];
    const float* bb2 = (const float*)d_in[17];
    float* out = (float*)d_out;

    // workspace carve-up
    char* ws = (char*)d_ws;
    size_t off = 0;
    auto carve = [&](size_t bytes) { void* p = ws + off; off += bytes; return p; };
    const size_t BND2 = (size_t)ROWS * DD * 2;       // 8 MB bf16 [8192,512]

    unsigned short* Xn   = (unsigned short*)carve(BND2);
    unsigned short* Yb   = (unsigned short*)carve(BND2);
    unsigned short* WqkvT= (unsigned short*)carve((size_t)3 * DD * DD * 2);
    unsigned short* WmT  = (unsigned short*)carve((size_t)DD * DD * 2);
    unsigned short* W1T  = (unsigned short*)carve((size_t)DD * DFF * 2);
    unsigned short* W2T  = (unsigned short*)carve((size_t)DFF * DD * 2);
    float*          bqkv = (float*)carve(1536 * 4);
    unsigned short* Qb   = (unsigned short*)carve(BND2);
    unsigned short* Kbf  = (unsigned short*)carve(BND2);
    unsigned short* Vtg  = (unsigned short*)carve(BND2);  // V^T [b*512+feat][token]
    float*          Hx   = (float*)carve((size_t)ROWS * DD * 4);
    unsigned short* G    = (unsigned short*)carve((size_t)ROWS * DFF * 2);
    unsigned short* Mh   = Xn;   // reuse: Xn dead after QKV
    unsigned short* Hn   = Yb;   // reuse: Yb dead after QKV

    unsigned short* WqT = WqkvT;
    unsigned short* WkT = WqkvT + (size_t)DD * DD;
    unsigned short* WvT = WqkvT + (size_t)2 * DD * DD;

    // 1. LN(X) -> Xn bf16 ; cast Y -> bf16 ; concat biases
    ln_kernel<<<ROWS, 256, 0, stream>>>(X, g0, b0, Xn);
    cast_bf16_kernel<<<(ROWS * DD / 4 + 255) / 256, 256, 0, stream>>>(Y, Yb, ROWS * DD / 4);
    bias_concat_kernel<<<6, 256, 0, stream>>>(bq, bk, bv, bqkv);

    // 2. transpose-cast weights to B^T bf16
    transpose_cast_kernel<<<dim3(DD / 32, DD / 32),  256, 0, stream>>>(Wq, WqT, DD, DD);
    transpose_cast_kernel<<<dim3(DD / 32, DD / 32),  256, 0, stream>>>(Wk, WkT, DD, DD);
    transpose_cast_kernel<<<dim3(DD / 32, DD / 32),  256, 0, stream>>>(Wv, WvT, DD, DD);
    transpose_cast_kernel<<<dim3(DD / 32, DD / 32),  256, 0, stream>>>(Wm, WmT, DD, DD);
    transpose_cast_kernel<<<dim3(DFF / 32, DD / 32), 256, 0, stream>>>(W1, W1T, DD, DFF);
    transpose_cast_kernel<<<dim3(DD / 32, DFF / 32), 256, 0, stream>>>(W2, W2T, DFF, DD);

    // 3. fused QKV projection
    gemm_bt<4><<<dim3(ROWS / 128, 12), 256, 0, stream>>>(
        Xn, Yb, WqkvT, bqkv, nullptr, nullptr, nullptr, nullptr,
        Qb, Kbf, Vtg, ROWS, 3 * DD, DD);

    // 4. attention (512 blocks: b*h*16 q-tiles of 128)
    flash_attn_kernel<<<BB * HH * (NN / 128), 256, 0, stream>>>(Qb, Kbf, Vtg, Mh);

    // 5. head mix + residual (Q) -> Hx fp32
    gemm_bt<1><<<dim3(ROWS / 128, DD / 128), 256, 0, stream>>>(
        Mh, nullptr, WmT, bm, Qb, nullptr, nullptr, Hx,
        nullptr, nullptr, nullptr, ROWS, DD, DD);

    // 6. LN(Hx) -> Hn bf16
    ln_kernel<<<ROWS, 256, 0, stream>>>(Hx, g1, b1, Hn);

    // 7. FFN1 + fast gelu -> G bf16
    gemm_bt<2><<<dim3(ROWS / 128, DFF / 128), 256, 0, stream>>>(
        Hn, nullptr, W1T, bb1, nullptr, nullptr, G, nullptr,
        nullptr, nullptr, nullptr, ROWS, DFF, DD);

    // 8. FFN2 + residual (Hx) -> out fp32
    gemm_bt<3><<<dim3(ROWS / 128, DD / 128), 256, 0, stream>>>(
        G, nullptr, W2T, bb2, nullptr, Hx, nullptr, out,
        nullptr, nullptr, nullptr, ROWS, DD, DFF);
}

// Round 5
// 358.781 us; speedup vs baseline: 1.1576x; 1.1576x over previous
//
#include <hip/hip_runtime.h>
#include <cmath>

// ---------------------------------------------------------------------------
// Types / helpers
// ---------------------------------------------------------------------------
typedef __attribute__((ext_vector_type(8))) short bf16x8;   // 8 bf16 = 4 VGPRs
typedef __attribute__((ext_vector_type(4))) float f32x4;

__device__ __forceinline__ unsigned short f2b(float f) {   // RNE (cold paths)
    union { float f; unsigned u; } c; c.f = f;
    unsigned r = (c.u + 0x7FFFu + ((c.u >> 16) & 1u)) >> 16;
    return (unsigned short)r;
}
__device__ __forceinline__ unsigned short f2b_hu(float f) { // round-half-up, 2 VALU
    union { float f; unsigned u; } c; c.f = f;
    return (unsigned short)((c.u + 0x8000u) >> 16);
}
__device__ __forceinline__ unsigned pk2(float a, float b) { // pack 2 bf16 (half-up)
    union { float f; unsigned u; } x, y; x.f = a; y.f = b;
    return ((x.u + 0x8000u) >> 16) | (((y.u + 0x8000u) >> 16) << 16);
}
__device__ __forceinline__ float b2f(unsigned short h) {
    union { unsigned u; float f; } c; c.u = ((unsigned)h) << 16;
    return c.f;
}

// async global->LDS 16B (wave-uniform LDS base + lane*16)
__device__ __forceinline__ void gl2lds16(const unsigned short* g, unsigned short* l) {
    __builtin_amdgcn_global_load_lds(
        (const __attribute__((address_space(1))) unsigned int*)(g),
        (__attribute__((address_space(3))) unsigned int*)(l),
        16, 0, 0);
}

// Problem constants
#define BB   4
#define NN   2048
#define DD   512
#define HH   8
#define DH   64
#define DFF  2048
#define ROWS (BB * NN)          // 8192
#define SCALE_QK 0.044194173824159216f   // 1/sqrt(512)

// ---------------------------------------------------------------------------
// LayerNorm (fp32 in) -> bf16 out.  One block (256 thr) per row of 512.
// ---------------------------------------------------------------------------
__global__ __launch_bounds__(256)
void ln_kernel(const float* __restrict__ X, const float* __restrict__ g,
               const float* __restrict__ be, unsigned short* __restrict__ out)
{
    __shared__ float sred[8];
    const int row = blockIdx.x;
    const int tid = threadIdx.x;
    const float* x = X + (size_t)row * DD;
    float x0 = x[tid], x1 = x[tid + 256];
    float s = x0 + x1, sq = x0 * x0 + x1 * x1;
#pragma unroll
    for (int off = 32; off; off >>= 1) {
        s  += __shfl_down(s,  off);
        sq += __shfl_down(sq, off);
    }
    const int wid = tid >> 6;
    if ((tid & 63) == 0) { sred[wid] = s; sred[4 + wid] = sq; }
    __syncthreads();
    float ts = 0.f, tq = 0.f;
#pragma unroll
    for (int i = 0; i < 4; ++i) { ts += sred[i]; tq += sred[4 + i]; }
    const float mean = ts * (1.0f / DD);
    const float var  = tq * (1.0f / DD) - mean * mean;
    const float rinv = rsqrtf(var + 1e-5f);
    unsigned short* o = out + (size_t)row * DD;
    o[tid]       = f2b((x0 - mean) * rinv * g[tid]       + be[tid]);
    o[tid + 256] = f2b((x1 - mean) * rinv * g[tid + 256] + be[tid + 256]);
}

// ---------------------------------------------------------------------------
// fp32 -> bf16 elementwise cast (4 elems/thread)
// ---------------------------------------------------------------------------
__global__ __launch_bounds__(256)
void cast_bf16_kernel(const float* __restrict__ in, unsigned short* __restrict__ out, int n4)
{
    int i = blockIdx.x * 256 + threadIdx.x;
    if (i < n4) {
        float4 v = ((const float4*)in)[i];
        ushort4 o;
        o.x = f2b(v.x); o.y = f2b(v.y); o.z = f2b(v.z); o.w = f2b(v.w);
        ((ushort4*)out)[i] = o;
    }
}

// ---------------------------------------------------------------------------
// ALL weight transposes in one launch (3072 tiles of 32x32):
//   t <  1024        : W1  (K=512,  Nn=2048) -> W1T
//   1024 <= t < 2048 : W2  (K=2048, Nn=512)  -> W2T
//   2048 <= t < 3072 : Wq|Wk|Wv -> WqkvT (contiguous), Wm -> WmT  (512x512 each)
// ---------------------------------------------------------------------------
__global__ __launch_bounds__(256)
void transpose_all_kernel(const float* __restrict__ Wq, const float* __restrict__ Wk,
                          const float* __restrict__ Wv, const float* __restrict__ Wm,
                          const float* __restrict__ W1, const float* __restrict__ W2,
                          unsigned short* __restrict__ WqkvT, unsigned short* __restrict__ WmT,
                          unsigned short* __restrict__ W1T, unsigned short* __restrict__ W2T)
{
    __shared__ float tile[32][33];
    const int t = blockIdx.x;
    const float* W; unsigned short* Wt; int K, Nn, n0, k0;
    if (t < 1024) {
        W = W1; Wt = W1T; K = DD; Nn = DFF;
        n0 = (t & 63) * 32; k0 = (t >> 6) * 32;
    } else if (t < 2048) {
        int u = t - 1024;
        W = W2; Wt = W2T; K = DFF; Nn = DD;
        n0 = (u & 15) * 32; k0 = (u >> 4) * 32;
    } else {
        int u = t - 2048;
        int m = u >> 8;            // 0..3 : Wq,Wk,Wv,Wm
        int v = u & 255;
        K = DD; Nn = DD;
        n0 = (v & 15) * 32; k0 = (v >> 4) * 32;
        if (m == 0)      { W = Wq; Wt = WqkvT; }
        else if (m == 1) { W = Wk; Wt = WqkvT + (size_t)DD * DD; }
        else if (m == 2) { W = Wv; Wt = WqkvT + (size_t)2 * DD * DD; }
        else             { W = Wm; Wt = WmT; }
    }
    const int tx = threadIdx.x & 31, ty = threadIdx.x >> 5;  // ty 0..7
#pragma unroll
    for (int i = 0; i < 4; ++i)
        tile[ty + i * 8][tx] = W[(size_t)(k0 + ty + i * 8) * Nn + n0 + tx];
    __syncthreads();
#pragma unroll
    for (int i = 0; i < 4; ++i)
        Wt[(size_t)(n0 + ty + i * 8) * K + k0 + tx] = f2b(tile[tx][ty + i * 8]);
}

// concat biases bq|bk|bv -> bqkv[1536]
__global__ __launch_bounds__(256)
void bias_concat_kernel(const float* __restrict__ bq, const float* __restrict__ bk,
                        const float* __restrict__ bv, float* __restrict__ o)
{
    int i = blockIdx.x * 256 + threadIdx.x;   // 0..1535
    float v = (i < 512) ? bq[i] : (i < 1024) ? bk[i - 512] : bv[i - 1024];
    o[i] = v;
}

// ---------------------------------------------------------------------------
// GEMM: C[M,N] = A[M,K] @ Bt[N,K]^T + bias, bf16 in, fp32 accumulate.
// MT x 128 tile (MT = 64 or 128), 256 threads (4 waves), BK=64 as two
// MT x 32 LDS halves, global_load_lds width-16 async staging.
// MT=64 doubles the grid for the 256-block shapes (mix/FFN2) -> 2 blocks/CU.
// MODE 1: += bf16 residual (resB), store fp32 (outF)            [mix]
// MODE 2: fast-tanh gelu, store bf16 (outB)                     [FFN1]
// MODE 3: += fp32 residual (resF), store fp32 (outF)            [FFN2]
// MODE 4: fused QKV, N=1536 (MT=128 only): col<512 -> Qb, <1024 -> Kbf,
//         else V transposed into Vtg[b*512+feat][token]; A=(by<4)?A0:A1.
// ---------------------------------------------------------------------------
template <int MODE, int MT>
__global__ __launch_bounds__(256)
void gemm_bt(const unsigned short* __restrict__ A0, const unsigned short* __restrict__ A1,
             const unsigned short* __restrict__ Bt,
             const float* __restrict__ bias,
             const unsigned short* __restrict__ resB, const float* __restrict__ resF,
             unsigned short* __restrict__ outB, float* __restrict__ outF,
             unsigned short* __restrict__ outQ, unsigned short* __restrict__ outK,
             unsigned short* __restrict__ outVt,
             int M, int N, int K)
{
    __shared__ __align__(16) unsigned short As[2][MT * 32];
    __shared__ __align__(16) unsigned short Bs[2][128 * 32];
    const int tid  = threadIdx.x;
    const int wave = tid >> 6, lane = tid & 63;
    const int quad = lane >> 4, l16 = lane & 15;
    const int MI  = MT / 32;               // 2 or 4 accumulator row-tiles
    const int RPW = MT / 4;                // A rows staged per wave
    const int wm = (wave & 1) * (MT / 2), wn = (wave >> 1) * 64;
    const int m0 = blockIdx.x * MT, n0 = blockIdx.y * 128;

    const unsigned short* A = (MODE == 4 && blockIdx.y >= 4) ? A1 : A0;

    const int srow = lane >> 2;
    const int sc8  = (lane & 3) * 8;
    const unsigned short* gA = A  + (size_t)(m0 + wave * RPW + srow) * K + sc8;
    const unsigned short* gB = Bt + (size_t)(n0 + wave * 32  + srow) * K + sc8;

    f32x4 acc[MI][4];
#pragma unroll
    for (int i = 0; i < MI; ++i)
#pragma unroll
        for (int j = 0; j < 4; ++j)
            acc[i][j] = (f32x4){0.f, 0.f, 0.f, 0.f};

    for (int kk = 0; kk < K; kk += 64) {
        __syncthreads();
#pragma unroll
        for (int ih = 0; ih < RPW / 16; ++ih)
#pragma unroll
            for (int half = 0; half < 2; ++half)
                gl2lds16(gA + (size_t)ih * 16 * K + half * 32 + kk,
                         &As[half][(wave * RPW + ih * 16) * 32]);
#pragma unroll
        for (int ih = 0; ih < 2; ++ih)
#pragma unroll
            for (int half = 0; half < 2; ++half)
                gl2lds16(gB + (size_t)ih * 16 * K + half * 32 + kk,
                         &Bs[half][(wave * 32 + ih * 16) * 32]);
        __syncthreads();
#pragma unroll
        for (int h = 0; h < 2; ++h) {
            bf16x8 a[MI], b[4];
#pragma unroll
            for (int i = 0; i < MI; ++i)
                a[i] = *(const bf16x8*)&As[h][(wm + i * 16 + l16) * 32 + quad * 8];
#pragma unroll
            for (int j = 0; j < 4; ++j)
                b[j] = *(const bf16x8*)&Bs[h][(wn + j * 16 + l16) * 32 + quad * 8];
#pragma unroll
            for (int i = 0; i < MI; ++i)
#pragma unroll
                for (int j = 0; j < 4; ++j)
                    acc[i][j] = __builtin_amdgcn_mfma_f32_16x16x32_bf16(a[i], b[j], acc[i][j], 0, 0, 0);
        }
    }

    // Epilogue. C/D layout: col = lane&15, row = quad*4 + reg.
#pragma unroll
    for (int i = 0; i < MI; ++i) {
#pragma unroll
        for (int j = 0; j < 4; ++j) {
            const int col  = n0 + wn + j * 16 + l16;
            const int row0 = m0 + wm + i * 16 + quad * 4;
            const float bsv = bias[col];
            if (MODE == 4) {
                if (col < DD) {
#pragma unroll
                    for (int r = 0; r < 4; ++r)
                        outQ[(size_t)(row0 + r) * DD + col] = f2b_hu(acc[i][j][r] + bsv);
                } else if (col < 2 * DD) {
#pragma unroll
                    for (int r = 0; r < 4; ++r)
                        outK[(size_t)(row0 + r) * DD + (col - DD)] = f2b_hu(acc[i][j][r] + bsv);
                } else {
                    const int feat = col - 2 * DD;
                    const int bb = row0 >> 11;
                    const int n  = row0 & (NN - 1);
                    ushort4 o;
                    o.x = f2b_hu(acc[i][j][0] + bsv);
                    o.y = f2b_hu(acc[i][j][1] + bsv);
                    o.z = f2b_hu(acc[i][j][2] + bsv);
                    o.w = f2b_hu(acc[i][j][3] + bsv);
                    *(ushort4*)&outVt[((size_t)bb * DD + feat) * NN + n] = o;
                }
            } else {
#pragma unroll
                for (int r = 0; r < 4; ++r) {
                    const size_t idx = (size_t)(row0 + r) * N + col;
                    float v = acc[i][j][r] + bsv;
                    if (MODE == 1) {
                        outF[idx] = v + b2f(resB[idx]);
                    } else if (MODE == 2) {
                        float u = 0.7978845608028654f * (v + 0.044715f * v * v * v);
                        float e = __expf(2.0f * u);
                        float t = 1.0f - 2.0f / (e + 1.0f);
                        outB[idx] = f2b_hu(0.5f * v * (1.0f + t));
                    } else {   // MODE 3
                        outF[idx] = v + resF[idx];
                    }
                }
            }
        }
    }
}

// ---------------------------------------------------------------------------
// Flash attention v5: block = (b, h, 128-q tile), 4 waves, wave owns 32 q
// (2 subtiles of 16).  K/V LDS-staged (v2-proven padded layout, register
// prefetch of next tile across compute), Q register-hoisted, S^T = K.Q^T so
// lane = one q column (scalar lsum).  Each K/V fragment read feeds 2 MFMAs
// (2 q-subtiles) -> LDS read per MFMA halved vs v2.  P via wave-private
// packed-dword LDS (v4-proven low-conflict), no barrier.  O accumulated
// as O^T, wave-private LDS transpose at the end.
// ---------------------------------------------------------------------------
#define ALD 72   // K/V LDS row stride (144B: +4-bank rotation per row)
#define PLD 33   // Pt row stride in dwords

__global__ __launch_bounds__(256)
void flash_attn_kernel(const unsigned short* __restrict__ Q,
                       const unsigned short* __restrict__ Kb,
                       const unsigned short* __restrict__ Vtg,
                       unsigned short* __restrict__ O)
{
    __shared__ __align__(16) unsigned short Ks[64 * ALD];     // 9.2 KB
    __shared__ __align__(16) unsigned short Vt[64 * ALD];     // 9.2 KB
    __shared__ __align__(16) unsigned int   Pt[4 * 32 * PLD]; // 16.9 KB

    const int tid  = threadIdx.x;
    const int wave = tid >> 6, lane = tid & 63;
    const int quad = lane >> 4, l16 = lane & 15;

    const int bid = blockIdx.x;
    const int qt = bid & 15;          // 16 q-tiles of 128
    const int bh = bid >> 4;
    const int b  = bh >> 3;
    const int h  = bh & 7;
    const size_t rowbase = (size_t)b * NN * DD;
    const int q0 = qt * 128 + wave * 32;   // this wave's q base
    const int hc = h * DH;
    unsigned int* myPt = &Pt[wave * 32 * PLD];

    // hoist Q B-frags (once per kernel): q = q0 + t*16 + l16, dh = hh*32+quad*8
    bf16x8 Qf[2][2];
#pragma unroll
    for (int t = 0; t < 2; ++t)
#pragma unroll
        for (int hh = 0; hh < 2; ++hh)
            Qf[t][hh] = *(const bf16x8*)&Q[rowbase + (size_t)(q0 + t * 16 + l16) * DD
                                           + hc + hh * 32 + quad * 8];

    f32x4 Oacc[2][4];   // [q-subtile][dh-tile]: O^T, col=q(l16), row=dh=16t2+4quad+r
#pragma unroll
    for (int t = 0; t < 2; ++t)
#pragma unroll
        for (int t2 = 0; t2 < 4; ++t2) Oacc[t][t2] = (f32x4){0.f, 0.f, 0.f, 0.f};
    float lsum[2] = {0.f, 0.f};

    // staging geometry (per thread: 2 x uint4 for K and for V)
    int srw[2], sc8[2];
#pragma unroll
    for (int i = 0; i < 2; ++i) { int e = tid + i * 256; srw[i] = e >> 3; sc8[i] = (e & 7) * 8; }
    const unsigned short* gKs = Kb  + rowbase + hc;
    const unsigned short* gVs = Vtg + ((size_t)b * DD + hc) * NN;

    uint4 kpre[2], vpre[2];
#pragma unroll
    for (int i = 0; i < 2; ++i) {
        kpre[i] = *(const uint4*)&gKs[(size_t)srw[i] * DD + sc8[i]];
        vpre[i] = *(const uint4*)&gVs[(size_t)srw[i] * NN + sc8[i]];
    }

    for (int kt = 0; kt < NN / 64; ++kt) {
        __syncthreads();   // all waves done reading Ks/Vt of previous iter
#pragma unroll
        for (int i = 0; i < 2; ++i) {
            *(uint4*)&Ks[srw[i] * ALD + sc8[i]] = kpre[i];
            *(uint4*)&Vt[srw[i] * ALD + sc8[i]] = vpre[i];
        }
        if (kt + 1 < NN / 64) {     // prefetch next tile; completes during compute
            const int kv0n = (kt + 1) * 64;
#pragma unroll
            for (int i = 0; i < 2; ++i) {
                kpre[i] = *(const uint4*)&gKs[(size_t)(kv0n + srw[i]) * DD + sc8[i]];
                vpre[i] = *(const uint4*)&gVs[(size_t)srw[i] * NN + kv0n + sc8[i]];
            }
        }
        __syncthreads();

        // ---- S^T tiles: St[t][j] over 16 kv x 16 q, each kf feeds 2 MFMAs ----
        f32x4 St[2][4];
#pragma unroll
        for (int t = 0; t < 2; ++t)
#pragma unroll
            for (int j = 0; j < 4; ++j) St[t][j] = (f32x4){0.f, 0.f, 0.f, 0.f};
#pragma unroll
        for (int j = 0; j < 4; ++j) {
#pragma unroll
            for (int hh = 0; hh < 2; ++hh) {
                bf16x8 kf = *(const bf16x8*)&Ks[(j * 16 + l16) * ALD + hh * 32 + quad * 8];
#pragma unroll
                for (int t = 0; t < 2; ++t)
                    St[t][j] = __builtin_amdgcn_mfma_f32_16x16x32_bf16(kf, Qf[t][hh], St[t][j], 0, 0, 0);
            }
        }

        // ---- exp(scale*S), scalar lsum, pack P rows into wave-private LDS ----
#pragma unroll
        for (int t = 0; t < 2; ++t) {
            unsigned int* rowp = &myPt[(t * 16 + l16) * PLD];
#pragma unroll
            for (int j = 0; j < 4; ++j) {
                float p0 = __expf(St[t][j][0] * SCALE_QK);
                float p1 = __expf(St[t][j][1] * SCALE_QK);
                float p2 = __expf(St[t][j][2] * SCALE_QK);
                float p3 = __expf(St[t][j][3] * SCALE_QK);
                lsum[t] += (p0 + p1) + (p2 + p3);
                rowp[j * 8 + quad * 2]     = pk2(p0, p1);
                rowp[j * 8 + quad * 2 + 1] = pk2(p2, p3);
            }
        }

        // ---- O^T += V^T · P^T : each vf feeds 2 MFMAs ----
#pragma unroll
        for (int ks = 0; ks < 2; ++ks) {
            bf16x8 pf[2];
#pragma unroll
            for (int t = 0; t < 2; ++t)
                pf[t] = *(const bf16x8*)&myPt[(t * 16 + l16) * PLD + ks * 16 + quad * 4];
#pragma unroll
            for (int t2 = 0; t2 < 4; ++t2) {
                bf16x8 vf = *(const bf16x8*)&Vt[(t2 * 16 + l16) * ALD + ks * 32 + quad * 8];
#pragma unroll
                for (int t = 0; t < 2; ++t)
                    Oacc[t][t2] = __builtin_amdgcn_mfma_f32_16x16x32_bf16(vf, pf[t], Oacc[t][t2], 0, 0, 0);
            }
        }
    }

    // reduce lsum across the 4 quads (same q = l16)
#pragma unroll
    for (int t = 0; t < 2; ++t) {
        lsum[t] += __shfl_xor(lsum[t], 16);
        lsum[t] += __shfl_xor(lsum[t], 32);
    }
    const float rl0 = 1.0f / lsum[0], rl1 = 1.0f / lsum[1];

    // transpose O^T -> O via wave-private LDS (reuse Pt), coalesced store
#pragma unroll
    for (int t = 0; t < 2; ++t) {
        const float rl = t ? rl1 : rl0;
        unsigned int* rowp = &myPt[(t * 16 + l16) * PLD];
#pragma unroll
        for (int t2 = 0; t2 < 4; ++t2) {
            rowp[t2 * 8 + quad * 2]     = pk2(Oacc[t][t2][0] * rl, Oacc[t][t2][1] * rl);
            rowp[t2 * 8 + quad * 2 + 1] = pk2(Oacc[t][t2][2] * rl, Oacc[t][t2][3] * rl);
        }
    }
#pragma unroll
    for (int ii = 0; ii < 4; ++ii) {
        int flat  = lane + ii * 64;       // 0..255
        int row   = flat >> 3;            // q within wave (0..31)
        int chunk = flat & 7;
        uint4 v = *(const uint4*)&myPt[row * PLD + chunk * 4];
        *(uint4*)&O[rowbase + (size_t)(q0 + row) * DD + hc + chunk * 8] = v;
    }
}

// ---------------------------------------------------------------------------
// Launch
// ---------------------------------------------------------------------------
extern "C" void kernel_launch(void* const* d_in, const int* in_sizes, int n_in,
                              void* d_out, int out_size, void* d_ws, size_t ws_size,
                              hipStream_t stream)
{
    (void)in_sizes; (void)n_in; (void)out_size; (void)ws_size;

    const float* X   = (const float*)d_in[0];
    const float* Y   = (const float*)d_in[1];
    const float* Wq  = (const float*)d_in[2];
    const float* bq  = (const float*)d_in[3];
    const float* Wk  = (const float*)d_in[4];
    const float* bk  = (const float*)d_in[5];
    const float* Wv  = (const float*)d_in[6];
    const float* bv  = (const float*)d_in[7];
    const float* Wm  = (const float*)d_in[8];
    const float* bm  = (const float*)d_in[9];
    const float* g0  = (const float*)d_in[10];
    const float* b0  = (const float*)d_in[11];
    const float* g1  = (const float*)d_in[12];
    const float* b1  = (const float*)d_in[13];
    const float* W1  = (const float*)d_in[14];
    const float* bb1 = (const float*)d_in[15];
    const float* W2  = (const float*)d_in[16];
    const float* bb2 = (const float*)d_in[17];
    float* out = (float*)d_out;

    // workspace carve-up
    char* ws = (char*)d_ws;
    size_t off = 0;
    auto carve = [&](size_t bytes) { void* p = ws + off; off += bytes; return p; };
    const size_t BND2 = (size_t)ROWS * DD * 2;       // 8 MB bf16 [8192,512]

    unsigned short* Xn   = (unsigned short*)carve(BND2);
    unsigned short* Yb   = (unsigned short*)carve(BND2);
    unsigned short* WqkvT= (unsigned short*)carve((size_t)3 * DD * DD * 2);
    unsigned short* WmT  = (unsigned short*)carve((size_t)DD * DD * 2);
    unsigned short* W1T  = (unsigned short*)carve((size_t)DD * DFF * 2);
    unsigned short* W2T  = (unsigned short*)carve((size_t)DFF * DD * 2);
    float*          bqkv = (float*)carve(1536 * 4);
    unsigned short* Qb   = (unsigned short*)carve(BND2);
    unsigned short* Kbf  = (unsigned short*)carve(BND2);
    unsigned short* Vtg  = (unsigned short*)carve(BND2);  // V^T [b*512+feat][token]
    float*          Hx   = (float*)carve((size_t)ROWS * DD * 4);
    unsigned short* G    = (unsigned short*)carve((size_t)ROWS * DFF * 2);
    unsigned short* Mh   = Xn;   // reuse: Xn dead after QKV
    unsigned short* Hn   = Yb;   // reuse: Yb dead after QKV

    // 1. LN(X) -> Xn bf16 ; cast Y -> bf16 ; concat biases
    ln_kernel<<<ROWS, 256, 0, stream>>>(X, g0, b0, Xn);
    cast_bf16_kernel<<<(ROWS * DD / 4 + 255) / 256, 256, 0, stream>>>(Y, Yb, ROWS * DD / 4);
    bias_concat_kernel<<<6, 256, 0, stream>>>(bq, bk, bv, bqkv);

    // 2. all weight transposes in one launch
    transpose_all_kernel<<<3072, 256, 0, stream>>>(
        Wq, Wk, Wv, Wm, W1, W2, WqkvT, WmT, W1T, W2T);

    // 3. fused QKV projection (768 blocks, 3/CU)
    gemm_bt<4, 128><<<dim3(ROWS / 128, 12), 256, 0, stream>>>(
        Xn, Yb, WqkvT, bqkv, nullptr, nullptr, nullptr, nullptr,
        Qb, Kbf, Vtg, ROWS, 3 * DD, DD);

    // 4. attention (512 blocks: b,h,16 q-tiles of 128)
    flash_attn_kernel<<<BB * HH * (NN / 128), 256, 0, stream>>>(Qb, Kbf, Vtg, Mh);

    // 5. head mix + residual (Q) -> Hx fp32   (MT=64 -> 512 blocks, 2/CU)
    gemm_bt<1, 64><<<dim3(ROWS / 64, DD / 128), 256, 0, stream>>>(
        Mh, nullptr, WmT, bm, Qb, nullptr, nullptr, Hx,
        nullptr, nullptr, nullptr, ROWS, DD, DD);

    // 6. LN(Hx) -> Hn bf16
    ln_kernel<<<ROWS, 256, 0, stream>>>(Hx, g1, b1, Hn);

    // 7. FFN1 + fast gelu -> G bf16  (1024 blocks, 4/CU)
    gemm_bt<2, 128><<<dim3(ROWS / 128, DFF / 128), 256, 0, stream>>>(
        Hn, nullptr, W1T, bb1, nullptr, nullptr, G, nullptr,
        nullptr, nullptr, nullptr, ROWS, DFF, DD);

    // 8. FFN2 + residual (Hx) -> out fp32  (MT=64 -> 512 blocks, 2/CU)
    gemm_bt<3, 64><<<dim3(ROWS / 64, DD / 128), 256, 0, stream>>>(
        G, nullptr, W2T, bb2, nullptr, Hx, nullptr, out,
        nullptr, nullptr, nullptr, ROWS, DD, DFF);
}

// Round 6
// 306.662 us; speedup vs baseline: 1.3544x; 1.1700x over previous
//
#include <hip/hip_runtime.h>
#include <cmath>

// ---------------------------------------------------------------------------
// Types / helpers
// ---------------------------------------------------------------------------
typedef __attribute__((ext_vector_type(8))) short bf16x8;   // 8 bf16 = 4 VGPRs
typedef __attribute__((ext_vector_type(4))) float f32x4;

__device__ __forceinline__ unsigned short f2b(float f) {   // RNE (cold paths)
    union { float f; unsigned u; } c; c.f = f;
    unsigned r = (c.u + 0x7FFFu + ((c.u >> 16) & 1u)) >> 16;
    return (unsigned short)r;
}
__device__ __forceinline__ unsigned short f2b_hu(float f) { // round-half-up, 2 VALU
    union { float f; unsigned u; } c; c.f = f;
    return (unsigned short)((c.u + 0x8000u) >> 16);
}
__device__ __forceinline__ unsigned pk2(float a, float b) { // pack 2 bf16 (half-up)
    union { float f; unsigned u; } x, y; x.f = a; y.f = b;
    return ((x.u + 0x8000u) >> 16) | (((y.u + 0x8000u) >> 16) << 16);
}
__device__ __forceinline__ float b2f(unsigned short h) {
    union { unsigned u; float f; } c; c.u = ((unsigned)h) << 16;
    return c.f;
}

// async global->LDS 16B (wave-uniform LDS base + lane*16)
__device__ __forceinline__ void gl2lds16(const unsigned short* g, unsigned short* l) {
    __builtin_amdgcn_global_load_lds(
        (const __attribute__((address_space(1))) unsigned int*)(g),
        (__attribute__((address_space(3))) unsigned int*)(l),
        16, 0, 0);
}

// Problem constants
#define BB   4
#define NN   2048
#define DD   512
#define HH   8
#define DH   64
#define DFF  2048
#define ROWS (BB * NN)          // 8192
#define SCALE_QK 0.044194173824159216f   // 1/sqrt(512)

// ---------------------------------------------------------------------------
// LayerNorm (fp32 in) -> bf16 out.  One block (256 thr) per row of 512.
// ---------------------------------------------------------------------------
__global__ __launch_bounds__(256)
void ln_kernel(const float* __restrict__ X, const float* __restrict__ g,
               const float* __restrict__ be, unsigned short* __restrict__ out)
{
    __shared__ float sred[8];
    const int row = blockIdx.x;
    const int tid = threadIdx.x;
    const float* x = X + (size_t)row * DD;
    float x0 = x[tid], x1 = x[tid + 256];
    float s = x0 + x1, sq = x0 * x0 + x1 * x1;
#pragma unroll
    for (int off = 32; off; off >>= 1) {
        s  += __shfl_down(s,  off);
        sq += __shfl_down(sq, off);
    }
    const int wid = tid >> 6;
    if ((tid & 63) == 0) { sred[wid] = s; sred[4 + wid] = sq; }
    __syncthreads();
    float ts = 0.f, tq = 0.f;
#pragma unroll
    for (int i = 0; i < 4; ++i) { ts += sred[i]; tq += sred[4 + i]; }
    const float mean = ts * (1.0f / DD);
    const float var  = tq * (1.0f / DD) - mean * mean;
    const float rinv = rsqrtf(var + 1e-5f);
    unsigned short* o = out + (size_t)row * DD;
    o[tid]       = f2b((x0 - mean) * rinv * g[tid]       + be[tid]);
    o[tid + 256] = f2b((x1 - mean) * rinv * g[tid + 256] + be[tid + 256]);
}

// ---------------------------------------------------------------------------
// fp32 -> bf16 elementwise cast (4 elems/thread)
// ---------------------------------------------------------------------------
__global__ __launch_bounds__(256)
void cast_bf16_kernel(const float* __restrict__ in, unsigned short* __restrict__ out, int n4)
{
    int i = blockIdx.x * 256 + threadIdx.x;
    if (i < n4) {
        float4 v = ((const float4*)in)[i];
        ushort4 o;
        o.x = f2b(v.x); o.y = f2b(v.y); o.z = f2b(v.z); o.w = f2b(v.w);
        ((ushort4*)out)[i] = o;
    }
}

// ---------------------------------------------------------------------------
// ALL weight transposes in one launch (3072 tiles of 32x32)
// ---------------------------------------------------------------------------
__global__ __launch_bounds__(256)
void transpose_all_kernel(const float* __restrict__ Wq, const float* __restrict__ Wk,
                          const float* __restrict__ Wv, const float* __restrict__ Wm,
                          const float* __restrict__ W1, const float* __restrict__ W2,
                          unsigned short* __restrict__ WqkvT, unsigned short* __restrict__ WmT,
                          unsigned short* __restrict__ W1T, unsigned short* __restrict__ W2T)
{
    __shared__ float tile[32][33];
    const int t = blockIdx.x;
    const float* W; unsigned short* Wt; int K, Nn, n0, k0;
    if (t < 1024) {
        W = W1; Wt = W1T; K = DD; Nn = DFF;
        n0 = (t & 63) * 32; k0 = (t >> 6) * 32;
    } else if (t < 2048) {
        int u = t - 1024;
        W = W2; Wt = W2T; K = DFF; Nn = DD;
        n0 = (u & 15) * 32; k0 = (u >> 4) * 32;
    } else {
        int u = t - 2048;
        int m = u >> 8;            // 0..3 : Wq,Wk,Wv,Wm
        int v = u & 255;
        K = DD; Nn = DD;
        n0 = (v & 15) * 32; k0 = (v >> 4) * 32;
        if (m == 0)      { W = Wq; Wt = WqkvT; }
        else if (m == 1) { W = Wk; Wt = WqkvT + (size_t)DD * DD; }
        else if (m == 2) { W = Wv; Wt = WqkvT + (size_t)2 * DD * DD; }
        else             { W = Wm; Wt = WmT; }
    }
    const int tx = threadIdx.x & 31, ty = threadIdx.x >> 5;  // ty 0..7
#pragma unroll
    for (int i = 0; i < 4; ++i)
        tile[ty + i * 8][tx] = W[(size_t)(k0 + ty + i * 8) * Nn + n0 + tx];
    __syncthreads();
#pragma unroll
    for (int i = 0; i < 4; ++i)
        Wt[(size_t)(n0 + ty + i * 8) * K + k0 + tx] = f2b(tile[tx][ty + i * 8]);
}

// concat biases bq|bk|bv -> bqkv[1536]
__global__ __launch_bounds__(256)
void bias_concat_kernel(const float* __restrict__ bq, const float* __restrict__ bk,
                        const float* __restrict__ bv, float* __restrict__ o)
{
    int i = blockIdx.x * 256 + threadIdx.x;   // 0..1535
    float v = (i < 512) ? bq[i] : (i < 1024) ? bk[i - 512] : bv[i - 1024];
    o[i] = v;
}

// ---------------------------------------------------------------------------
// GEMM: C[M,N] = A[M,K] @ Bt[N,K]^T + bias, bf16 in, fp32 accumulate.
// MT x 128 tile (MT = 64 or 128), 256 threads (4 waves), BK=64 as two
// MT x 32 LDS halves, global_load_lds width-16 async staging.
// MODE 1: += bf16 residual (resB), store fp32 (outF)            [mix]
// MODE 2: fast-tanh gelu, store bf16 (outB)                     [FFN1]
// MODE 3: += fp32 residual (resF), store fp32 (outF)            [FFN2]
// MODE 4: fused QKV, N=1536 (MT=128): col<512->Qb, <1024->Kbf, else V
//         transposed into Vtg[b*512+feat][token]; A=(by<4)?A0:A1.
// ---------------------------------------------------------------------------
template <int MODE, int MT>
__global__ __launch_bounds__(256)
void gemm_bt(const unsigned short* __restrict__ A0, const unsigned short* __restrict__ A1,
             const unsigned short* __restrict__ Bt,
             const float* __restrict__ bias,
             const unsigned short* __restrict__ resB, const float* __restrict__ resF,
             unsigned short* __restrict__ outB, float* __restrict__ outF,
             unsigned short* __restrict__ outQ, unsigned short* __restrict__ outK,
             unsigned short* __restrict__ outVt,
             int M, int N, int K)
{
    __shared__ __align__(16) unsigned short As[2][MT * 32];
    __shared__ __align__(16) unsigned short Bs[2][128 * 32];
    const int tid  = threadIdx.x;
    const int wave = tid >> 6, lane = tid & 63;
    const int quad = lane >> 4, l16 = lane & 15;
    const int MI  = MT / 32;               // 2 or 4 accumulator row-tiles
    const int RPW = MT / 4;                // A rows staged per wave
    const int wm = (wave & 1) * (MT / 2), wn = (wave >> 1) * 64;
    const int m0 = blockIdx.x * MT, n0 = blockIdx.y * 128;

    const unsigned short* A = (MODE == 4 && blockIdx.y >= 4) ? A1 : A0;

    const int srow = lane >> 2;
    const int sc8  = (lane & 3) * 8;
    const unsigned short* gA = A  + (size_t)(m0 + wave * RPW + srow) * K + sc8;
    const unsigned short* gB = Bt + (size_t)(n0 + wave * 32  + srow) * K + sc8;

    f32x4 acc[MI][4];
#pragma unroll
    for (int i = 0; i < MI; ++i)
#pragma unroll
        for (int j = 0; j < 4; ++j)
            acc[i][j] = (f32x4){0.f, 0.f, 0.f, 0.f};

    for (int kk = 0; kk < K; kk += 64) {
        __syncthreads();
#pragma unroll
        for (int ih = 0; ih < RPW / 16; ++ih)
#pragma unroll
            for (int half = 0; half < 2; ++half)
                gl2lds16(gA + (size_t)ih * 16 * K + half * 32 + kk,
                         &As[half][(wave * RPW + ih * 16) * 32]);
#pragma unroll
        for (int ih = 0; ih < 2; ++ih)
#pragma unroll
            for (int half = 0; half < 2; ++half)
                gl2lds16(gB + (size_t)ih * 16 * K + half * 32 + kk,
                         &Bs[half][(wave * 32 + ih * 16) * 32]);
        __syncthreads();
#pragma unroll
        for (int h = 0; h < 2; ++h) {
            bf16x8 a[MI], b[4];
#pragma unroll
            for (int i = 0; i < MI; ++i)
                a[i] = *(const bf16x8*)&As[h][(wm + i * 16 + l16) * 32 + quad * 8];
#pragma unroll
            for (int j = 0; j < 4; ++j)
                b[j] = *(const bf16x8*)&Bs[h][(wn + j * 16 + l16) * 32 + quad * 8];
#pragma unroll
            for (int i = 0; i < MI; ++i)
#pragma unroll
                for (int j = 0; j < 4; ++j)
                    acc[i][j] = __builtin_amdgcn_mfma_f32_16x16x32_bf16(a[i], b[j], acc[i][j], 0, 0, 0);
        }
    }

    // Epilogue. C/D layout: col = lane&15, row = quad*4 + reg.
#pragma unroll
    for (int i = 0; i < MI; ++i) {
#pragma unroll
        for (int j = 0; j < 4; ++j) {
            const int col  = n0 + wn + j * 16 + l16;
            const int row0 = m0 + wm + i * 16 + quad * 4;
            const float bsv = bias[col];
            if (MODE == 4) {
                if (col < DD) {
#pragma unroll
                    for (int r = 0; r < 4; ++r)
                        outQ[(size_t)(row0 + r) * DD + col] = f2b_hu(acc[i][j][r] + bsv);
                } else if (col < 2 * DD) {
#pragma unroll
                    for (int r = 0; r < 4; ++r)
                        outK[(size_t)(row0 + r) * DD + (col - DD)] = f2b_hu(acc[i][j][r] + bsv);
                } else {
                    const int feat = col - 2 * DD;
                    const int bb = row0 >> 11;
                    const int n  = row0 & (NN - 1);
                    ushort4 o;
                    o.x = f2b_hu(acc[i][j][0] + bsv);
                    o.y = f2b_hu(acc[i][j][1] + bsv);
                    o.z = f2b_hu(acc[i][j][2] + bsv);
                    o.w = f2b_hu(acc[i][j][3] + bsv);
                    *(ushort4*)&outVt[((size_t)bb * DD + feat) * NN + n] = o;
                }
            } else {
#pragma unroll
                for (int r = 0; r < 4; ++r) {
                    const size_t idx = (size_t)(row0 + r) * N + col;
                    float v = acc[i][j][r] + bsv;
                    if (MODE == 1) {
                        outF[idx] = v + b2f(resB[idx]);
                    } else if (MODE == 2) {
                        float u = 0.7978845608028654f * (v + 0.044715f * v * v * v);
                        float e = __expf(2.0f * u);
                        float t = 1.0f - 2.0f / (e + 1.0f);
                        outB[idx] = f2b_hu(0.5f * v * (1.0f + t));
                    } else {   // MODE 3
                        outF[idx] = v + resF[idx];
                    }
                }
            }
        }
    }
}

// ---------------------------------------------------------------------------
// Flash attention v6: block = (b, h, 64-q tile), 128 THREADS / 2 WAVES,
// grid 1024 (4 blocks/CU).  Each wave owns 32 q (2 subtiles of 16); Q frags
// hoisted + pre-scaled in registers, so every K/V LDS fragment feeds 2 MFMAs
// (LDS-read per MFMA halved vs v2).  K/V staged v2-style (synchronous uint4
// round-trip, padded ALD rows).  S^T = K·Q^T -> lane = one q column: scalar
// lsum, P via wave-private packed-dword LDS (no barrier, low conflict).
// O accumulated as O^T, wave-private LDS transpose at end.
// __launch_bounds__(128,2): 256-VGPR budget, prevents the v5 spill.
// ---------------------------------------------------------------------------
#define ALD 72   // K/V LDS row stride (144B: +4-bank rotation per row)
#define PLD 33   // Pt row stride in dwords

__global__ __launch_bounds__(128, 2)
void flash_attn_kernel(const unsigned short* __restrict__ Q,
                       const unsigned short* __restrict__ Kb,
                       const unsigned short* __restrict__ Vtg,
                       unsigned short* __restrict__ O)
{
    __shared__ __align__(16) unsigned short Ks[64 * ALD];     // 9.2 KB
    __shared__ __align__(16) unsigned short Vt[64 * ALD];     // 9.2 KB
    __shared__ __align__(16) unsigned int   Pt[2 * 32 * PLD]; // 8.4 KB

    const int tid  = threadIdx.x;
    const int wave = tid >> 6, lane = tid & 63;
    const int quad = lane >> 4, l16 = lane & 15;

    const int bid = blockIdx.x;
    const int qt = bid & 31;          // 32 q-tiles of 64
    const int bh = bid >> 5;
    const int b  = bh >> 3;
    const int h  = bh & 7;
    const size_t rowbase = (size_t)b * NN * DD;
    const int q0 = qt * 64 + wave * 32;    // this wave's q base (32 q)
    const int hc = h * DH;
    unsigned int* myPt = &Pt[wave * 32 * PLD];

    // hoist Q B-frags, pre-scaled by 1/sqrt(512):
    // q = q0 + t*16 + l16, dh = hh*32 + quad*8
    bf16x8 Qf[2][2];
#pragma unroll
    for (int t = 0; t < 2; ++t)
#pragma unroll
        for (int hh = 0; hh < 2; ++hh) {
            union { bf16x8 v; unsigned short s[8]; unsigned u[4]; } raw, sc;
            raw.v = *(const bf16x8*)&Q[rowbase + (size_t)(q0 + t * 16 + l16) * DD
                                        + hc + hh * 32 + quad * 8];
#pragma unroll
            for (int p = 0; p < 4; ++p)
                sc.u[p] = pk2(b2f(raw.s[2 * p]) * SCALE_QK, b2f(raw.s[2 * p + 1]) * SCALE_QK);
            Qf[t][hh] = sc.v;
        }

    f32x4 Oacc[2][4];   // [q-subtile][dh-tile]: O^T, col=q(l16), row=dh=16t2+4quad+r
#pragma unroll
    for (int t = 0; t < 2; ++t)
#pragma unroll
        for (int t2 = 0; t2 < 4; ++t2) Oacc[t][t2] = (f32x4){0.f, 0.f, 0.f, 0.f};
    float lsum[2] = {0.f, 0.f};

    // staging geometry: 128 threads x 4 uint4 each for K and V (64 rows x 64)
    int srw[4], sc8[4];
#pragma unroll
    for (int i = 0; i < 4; ++i) { int e = tid + i * 128; srw[i] = e >> 3; sc8[i] = (e & 7) * 8; }
    const unsigned short* gKs = Kb  + rowbase + hc;
    const unsigned short* gVs = Vtg + ((size_t)b * DD + hc) * NN;

    for (int kt = 0; kt < NN / 64; ++kt) {
        const int kv0 = kt * 64;
        __syncthreads();   // all waves done reading Ks/Vt of previous iter
#pragma unroll
        for (int i = 0; i < 4; ++i) {
            *(uint4*)&Ks[srw[i] * ALD + sc8[i]] =
                *(const uint4*)&gKs[(size_t)(kv0 + srw[i]) * DD + sc8[i]];
            *(uint4*)&Vt[srw[i] * ALD + sc8[i]] =
                *(const uint4*)&gVs[(size_t)srw[i] * NN + kv0 + sc8[i]];
        }
        __syncthreads();

        // ---- S^T: St[t][j] (16 kv x 16 q); each kf feeds 2 MFMAs ----
        f32x4 St[2][4];
#pragma unroll
        for (int t = 0; t < 2; ++t)
#pragma unroll
            for (int j = 0; j < 4; ++j) St[t][j] = (f32x4){0.f, 0.f, 0.f, 0.f};
#pragma unroll
        for (int j = 0; j < 4; ++j) {
#pragma unroll
            for (int hh = 0; hh < 2; ++hh) {
                bf16x8 kf = *(const bf16x8*)&Ks[(j * 16 + l16) * ALD + hh * 32 + quad * 8];
#pragma unroll
                for (int t = 0; t < 2; ++t)
                    St[t][j] = __builtin_amdgcn_mfma_f32_16x16x32_bf16(kf, Qf[t][hh], St[t][j], 0, 0, 0);
            }
        }

        // ---- exp (scale pre-folded into Q), scalar lsum, pack P^T rows ----
#pragma unroll
        for (int t = 0; t < 2; ++t) {
            unsigned int* rowp = &myPt[(t * 16 + l16) * PLD];
#pragma unroll
            for (int j = 0; j < 4; ++j) {
                float p0 = __expf(St[t][j][0]);
                float p1 = __expf(St[t][j][1]);
                float p2 = __expf(St[t][j][2]);
                float p3 = __expf(St[t][j][3]);
                lsum[t] += (p0 + p1) + (p2 + p3);
                rowp[j * 8 + quad * 2]     = pk2(p0, p1);
                rowp[j * 8 + quad * 2 + 1] = pk2(p2, p3);
            }
        }

        // ---- O^T += V^T · P^T : each vf feeds 2 MFMAs ----
#pragma unroll
        for (int ks = 0; ks < 2; ++ks) {
            bf16x8 pf[2];
#pragma unroll
            for (int t = 0; t < 2; ++t)
                pf[t] = *(const bf16x8*)&myPt[(t * 16 + l16) * PLD + ks * 16 + quad * 4];
#pragma unroll
            for (int t2 = 0; t2 < 4; ++t2) {
                bf16x8 vf = *(const bf16x8*)&Vt[(t2 * 16 + l16) * ALD + ks * 32 + quad * 8];
#pragma unroll
                for (int t = 0; t < 2; ++t)
                    Oacc[t][t2] = __builtin_amdgcn_mfma_f32_16x16x32_bf16(vf, pf[t], Oacc[t][t2], 0, 0, 0);
            }
        }
    }

    // reduce lsum across the 4 quads (same q = l16)
#pragma unroll
    for (int t = 0; t < 2; ++t) {
        lsum[t] += __shfl_xor(lsum[t], 16);
        lsum[t] += __shfl_xor(lsum[t], 32);
    }
    const float rl0 = 1.0f / lsum[0], rl1 = 1.0f / lsum[1];

    // transpose O^T -> O via wave-private LDS (reuse Pt), coalesced store
#pragma unroll
    for (int t = 0; t < 2; ++t) {
        const float rl = t ? rl1 : rl0;
        unsigned int* rowp = &myPt[(t * 16 + l16) * PLD];
#pragma unroll
        for (int t2 = 0; t2 < 4; ++t2) {
            rowp[t2 * 8 + quad * 2]     = pk2(Oacc[t][t2][0] * rl, Oacc[t][t2][1] * rl);
            rowp[t2 * 8 + quad * 2 + 1] = pk2(Oacc[t][t2][2] * rl, Oacc[t][t2][3] * rl);
        }
    }
#pragma unroll
    for (int ii = 0; ii < 4; ++ii) {
        int flat  = lane + ii * 64;       // 0..255 within wave
        int row   = flat >> 3;            // q within wave (0..31)
        int chunk = flat & 7;
        uint4 v = *(const uint4*)&myPt[row * PLD + chunk * 4];
        *(uint4*)&O[rowbase + (size_t)(q0 + row) * DD + hc + chunk * 8] = v;
    }
}

// ---------------------------------------------------------------------------
// Launch
// ---------------------------------------------------------------------------
extern "C" void kernel_launch(void* const* d_in, const int* in_sizes, int n_in,
                              void* d_out, int out_size, void* d_ws, size_t ws_size,
                              hipStream_t stream)
{
    (void)in_sizes; (void)n_in; (void)out_size; (void)ws_size;

    const float* X   = (const float*)d_in[0];
    const float* Y   = (const float*)d_in[1];
    const float* Wq  = (const float*)d_in[2];
    const float* bq  = (const float*)d_in[3];
    const float* Wk  = (const float*)d_in[4];
    const float* bk  = (const float*)d_in[5];
    const float* Wv  = (const float*)d_in[6];
    const float* bv  = (const float*)d_in[7];
    const float* Wm  = (const float*)d_in[8];
    const float* bm  = (const float*)d_in[9];
    const float* g0  = (const float*)d_in[10];
    const float* b0  = (const float*)d_in[11];
    const float* g1  = (const float*)d_in[12];
    const float* b1  = (const float*)d_in[13];
    const float* W1  = (const float*)d_in[14];
    const float* bb1 = (const float*)d_in[15];
    const float* W2  = (const float*)d_in[16];
    const float* bb2 = (const float*)d_in[17];
    float* out = (float*)d_out;

    // workspace carve-up
    char* ws = (char*)d_ws;
    size_t off = 0;
    auto carve = [&](size_t bytes) { void* p = ws + off; off += bytes; return p; };
    const size_t BND2 = (size_t)ROWS * DD * 2;       // 8 MB bf16 [8192,512]

    unsigned short* Xn   = (unsigned short*)carve(BND2);
    unsigned short* Yb   = (unsigned short*)carve(BND2);
    unsigned short* WqkvT= (unsigned short*)carve((size_t)3 * DD * DD * 2);
    unsigned short* WmT  = (unsigned short*)carve((size_t)DD * DD * 2);
    unsigned short* W1T  = (unsigned short*)carve((size_t)DD * DFF * 2);
    unsigned short* W2T  = (unsigned short*)carve((size_t)DFF * DD * 2);
    float*          bqkv = (float*)carve(1536 * 4);
    unsigned short* Qb   = (unsigned short*)carve(BND2);
    unsigned short* Kbf  = (unsigned short*)carve(BND2);
    unsigned short* Vtg  = (unsigned short*)carve(BND2);  // V^T [b*512+feat][token]
    float*          Hx   = (float*)carve((size_t)ROWS * DD * 4);
    unsigned short* G    = (unsigned short*)carve((size_t)ROWS * DFF * 2);
    unsigned short* Mh   = Xn;   // reuse: Xn dead after QKV
    unsigned short* Hn   = Yb;   // reuse: Yb dead after QKV

    // 1. LN(X) -> Xn bf16 ; cast Y -> bf16 ; concat biases
    ln_kernel<<<ROWS, 256, 0, stream>>>(X, g0, b0, Xn);
    cast_bf16_kernel<<<(ROWS * DD / 4 + 255) / 256, 256, 0, stream>>>(Y, Yb, ROWS * DD / 4);
    bias_concat_kernel<<<6, 256, 0, stream>>>(bq, bk, bv, bqkv);

    // 2. all weight transposes in one launch
    transpose_all_kernel<<<3072, 256, 0, stream>>>(
        Wq, Wk, Wv, Wm, W1, W2, WqkvT, WmT, W1T, W2T);

    // 3. fused QKV projection (768 blocks, 3/CU)
    gemm_bt<4, 128><<<dim3(ROWS / 128, 12), 256, 0, stream>>>(
        Xn, Yb, WqkvT, bqkv, nullptr, nullptr, nullptr, nullptr,
        Qb, Kbf, Vtg, ROWS, 3 * DD, DD);

    // 4. attention (1024 blocks of 128 threads: b,h,32 q-tiles of 64)
    flash_attn_kernel<<<BB * HH * (NN / 64), 128, 0, stream>>>(Qb, Kbf, Vtg, Mh);

    // 5. head mix + residual (Q) -> Hx fp32   (MT=64 -> 512 blocks, 2/CU)
    gemm_bt<1, 64><<<dim3(ROWS / 64, DD / 128), 256, 0, stream>>>(
        Mh, nullptr, WmT, bm, Qb, nullptr, nullptr, Hx,
        nullptr, nullptr, nullptr, ROWS, DD, DD);

    // 6. LN(Hx) -> Hn bf16
    ln_kernel<<<ROWS, 256, 0, stream>>>(Hx, g1, b1, Hn);

    // 7. FFN1 + fast gelu -> G bf16  (1024 blocks, 4/CU)
    gemm_bt<2, 128><<<dim3(ROWS / 128, DFF / 128), 256, 0, stream>>>(
        Hn, nullptr, W1T, bb1, nullptr, nullptr, G, nullptr,
        nullptr, nullptr, nullptr, ROWS, DFF, DD);

    // 8. FFN2 + residual (Hx) -> out fp32  (MT=64 -> 512 blocks, 2/CU)
    gemm_bt<3, 64><<<dim3(ROWS / 64, DD / 128), 256, 0, stream>>>(
        G, nullptr, W2T, bb2, nullptr, Hx, nullptr, out,
        nullptr, nullptr, nullptr, ROWS, DD, DFF);
}